// Round 18
// baseline (555.722 us; speedup 1.0000x reference)
//
#include <hip/hip_runtime.h>
#include <hip/hip_bf16.h>
#include <math.h>

// Problem dims
#define BB 8
#define TT 16
#define HH 112
#define WW 112
#define CC 3
#define FF 16
#define HP 56
#define WP 56
#define HO 54
#define WO 54
#define NC 6

#define NPIX (BB*HO*WO)               // 23328
#define SPIX (HO*WO)                  // 2916
#define NPT  (BB*TT*SPIX)             // 373248  (b,t,pixel)
#define POOLED_BF16  (128*56*56*16)   // 6,422,528 bf16

// xpad: per-frame bf16 rows with halo + pad: 118 rows x 360 elems
#define XROW 360
#define XFRM (118*XROW)               // 42,480
#define XPAD_ELEMS (128*XFRM)         // 5,437,440 per parity copy

typedef __attribute__((ext_vector_type(8))) short s8v;   // 8 bf16 (4 VGPRs)
typedef __attribute__((ext_vector_type(4))) float f4v;   // MFMA acc

__device__ __forceinline__ float hsig(float x) {
    return fminf(fmaxf(0.2f*x + 0.5f, 0.0f), 1.0f);
}
__device__ __forceinline__ unsigned pk2(float lo, float hi) {
    union { __hip_bfloat16 h; unsigned short u; } a, b;
    a.h = __float2bfloat16(lo); b.h = __float2bfloat16(hi);
    return ((unsigned)b.u << 16) | (unsigned)a.u;
}
__device__ __forceinline__ float bf2f(unsigned short u) {
    union { unsigned v; float f; } x; x.v = ((unsigned)u) << 16; return x.f;
}
__device__ __forceinline__ unsigned short f2bfu(float f) {
    union { __hip_bfloat16 h; unsigned short u; } v;
    v.h = __float2bfloat16(f); return v.u;
}

// Kernel 0a: prepack a [3,3,16,64] weight tensor into MFMA B-fragment order
// (K=144 pad 160): out[nt][ks][lane][j]. Used for BOTH wk and wr.
__global__ __launch_bounds__(256) void w_prepack_kernel(
    const float* __restrict__ w, __hip_bfloat16* __restrict__ wb)
{
    int i = blockIdx.x * 256 + threadIdx.x;        // 40*256 = 10240 exact
    int j    = i & 7;
    int lane = (i >> 3) & 63;
    int ks   = (i >> 9) % 5;
    int nt   = (i >> 9) / 5;
    int k = ks*32 + ((lane >> 4) & 3)*8 + j;
    int n = nt*16 + (lane & 15);
    float v = 0.f;
    if (k < 144) {
        int tap = k >> 4, ci = k & 15;
        v = w[tap*1024 + ci*64 + n];
    }
    wb[i] = __float2bfloat16(v);
}

// Kernel 0b: prepack conv weights [7,7,3,16] (K = 7 rows x 24, pad 192).
__global__ __launch_bounds__(256) void cw_prepack_kernel(
    const float* __restrict__ cw, __hip_bfloat16* __restrict__ cwb)
{
    int i = blockIdx.x * 256 + threadIdx.x;        // 12*256 = 3072 exact
    int j    = i & 7;
    int lane = (i >> 3) & 63;
    int ks   = i >> 9;                             // 0..5
    int k = ks*32 + ((lane >> 4) & 3)*8 + j;
    int n = lane & 15;
    float v = 0.f;
    if (k < 168) {
        int row = k / 24, idx = k % 24;
        if (idx < 21) {
            int kx = idx / 3, ci = idx % 3;
            v = cw[((row*7 + kx)*3 + ci)*16 + n];
        }
    }
    cwb[i] = __float2bfloat16(v);
}

// Kernel 0c: build bf16 padded x rows, TWO parity-shifted copies.
__global__ __launch_bounds__(256) void xpad_kernel(
    const float* __restrict__ x,
    __hip_bfloat16* __restrict__ xp0,
    __hip_bfloat16* __restrict__ xp1)
{
    int idx = blockIdx.x * 256 + threadIdx.x;      // 5310*256 = 1,359,360 exact
    int e4 = idx % 90;
    int rr = (idx / 90) % 118;
    int fr = idx / (90*118);
    int e0 = e4 * 4;
    int ir = rr - 3;
    const float* xf = x + (size_t)fr * (112*336);
    bool rowok = (ir >= 0) & (ir < 112);

    float v[5];
    #pragma unroll
    for (int i = 0; i < 5; ++i) {
        int s = e0 - 1 + i;
        bool ok = rowok & (s >= 9) & (s < 345);
        v[i] = ok ? xf[ir*336 + (s - 9)] : 0.f;
    }
    size_t o = ((size_t)fr*118 + rr) * XROW + e0;
    uint2 a0, a1;
    a0.x = pk2(v[1], v[2]); a0.y = pk2(v[3], v[4]);
    a1.x = pk2(v[0], v[1]); a1.y = pk2(v[2], v[3]);
    *(uint2*)&xp0[o] = a0;
    *(uint2*)&xp1[o] = a1;
}

// Kernel 1: conv 7x7 + bias + relu + maxpool via MFMA (R16) + XCD-contiguous
// block swizzle: vb = (bid&7)*3136 + (bid>>3) gives each XCD 16 whole frames
// -> each frame fetched by ONE XCD's L2 (R16: 56.8 MB fetched vs 21.7 ideal,
// 2.6x refetch from round-robin dispatch).
__global__ __launch_bounds__(256, 8) void conv_mfma_kernel(
    const __hip_bfloat16* __restrict__ xp0,
    const __hip_bfloat16* __restrict__ xp1,
    const __hip_bfloat16* __restrict__ cwb,  // [6][64][8]
    const float* __restrict__ cb,            // [16]
    __hip_bfloat16* __restrict__ pooled)     // [128,56,56,16] bf16
{
    int vb = (blockIdx.x & 7) * 3136 + (blockIdx.x >> 3);   // 25088 = 8*3136
    int w = (vb << 2) + (threadIdx.x >> 6);  // wave id 0..100351
    int lane = threadIdx.x & 63;
    int quad = lane >> 4;
    int fr = w / 784;
    int q  = w % 784;
    int p0 = q << 2;
    int m  = lane & 15;
    int pp = p0 + (m >> 2);
    int pos = m & 3;
    int pr = pp / 56, pc = pp % 56;
    int oh = 2*pr + (pos >> 1);
    int ow = 2*pc + (pos & 1);

    const __hip_bfloat16* xpc = (ow & 1) ? xp1 : xp0;
    const __hip_bfloat16* xrow = xpc + (size_t)fr*XFRM + ow*3 + (ow & 1);

    f4v acc = {0.f,0.f,0.f,0.f};
    const s8v* wb = (const s8v*)cwb;
    #pragma unroll
    for (int ks = 0; ks < 6; ++ks) {
        int blk = ks*4 + quad;
        s8v a = (s8v){0,0,0,0,0,0,0,0};
        if (blk < 21) {
            int row = blk / 3;
            int off = (blk % 3) * 8;
            a = *(const s8v*)(xrow + (size_t)(oh + row)*XROW + off);
        }
        acc = __builtin_amdgcn_mfma_f32_16x16x32_bf16(a, wb[ks*64 + lane], acc, 0,0,0);
    }

    int nlo = lane & 15;
    float* ap = (float*)&acc;
    float mx = fmaxf(fmaxf(ap[0], ap[1]), fmaxf(ap[2], ap[3]));
    float vv = fmaxf(mx + cb[nlo], 0.f);
    ((unsigned short*)pooled)[((size_t)fr*3136 + p0 + quad)*16 + nlo] = f2bfu(vv);
}

// Kernel 2a: zx via MFMA (R14, verified). One wave = 16 pt x 64 gates.
__global__ __launch_bounds__(256, 4) void zx_mfma_kernel(
    const __hip_bfloat16* __restrict__ pooled,  // [128][56][56][16] bf16
    const __hip_bfloat16* __restrict__ wkb,     // [4][5][64][8] bf16
    __hip_bfloat16* __restrict__ zx)            // [64][373248] bf16
{
    int wid  = (blockIdx.x << 2) + (threadIdx.x >> 6);  // 0..23327
    int lane = threadIdx.x & 63;
    int quad = lane >> 4;
    int pt0  = wid << 4;
    int m    = pt0 + (lane & 15);

    int b  = m / (TT*SPIX);
    int rt = m % (TT*SPIX);
    int tt = rt / SPIX;
    int r  = rt % SPIX;
    int oh = r / WO, ow = r % WO;
    const __hip_bfloat16* pf = pooled + (size_t)(b*TT + tt) * (HP*WP*16);

    f4v acc0 = {0.f,0.f,0.f,0.f}, acc1 = acc0, acc2 = acc0, acc3 = acc0;
    const s8v* wb = (const s8v*)wkb;

    #pragma unroll
    for (int ks = 0; ks < 5; ++ks) {
        int blk = ks*4 + quad;
        s8v a;
        if (blk < 18) {
            int tap = blk >> 1, half = blk & 1;
            int ky = tap / 3, kx = tap - ky*3;
            a = *(const s8v*)(pf + ((size_t)(oh+ky)*WP + (ow+kx))*16 + half*8);
        } else {
            a = (s8v){0,0,0,0,0,0,0,0};
        }
        acc0 = __builtin_amdgcn_mfma_f32_16x16x32_bf16(a, wb[(0*5+ks)*64 + lane], acc0, 0,0,0);
        acc1 = __builtin_amdgcn_mfma_f32_16x16x32_bf16(a, wb[(1*5+ks)*64 + lane], acc1, 0,0,0);
        acc2 = __builtin_amdgcn_mfma_f32_16x16x32_bf16(a, wb[(2*5+ks)*64 + lane], acc2, 0,0,0);
        acc3 = __builtin_amdgcn_mfma_f32_16x16x32_bf16(a, wb[(3*5+ks)*64 + lane], acc3, 0,0,0);
    }

    int nlo = lane & 15;
    size_t prow = (size_t)pt0 + quad*4;
    f4v accs[4] = {acc0, acc1, acc2, acc3};
    #pragma unroll
    for (int nt = 0; nt < 4; ++nt) {
        int n = nt*16 + nlo;
        uint2 u;
        u.x = pk2(accs[nt].x, accs[nt].y);
        u.y = pk2(accs[nt].z, accs[nt].w);
        *(uint2*)&zx[(size_t)n * NPT + prow] = u;
    }
}

// Kernel 2b: TWO ConvLSTM steps per launch via halo recompute + MFMA.
// Block = 8x8 interior region x 16 ch, 4 waves. Phase A: h(t0),c(t0) on the
// 10x10 extended region (7 m-tiles over 4 waves -> wave count per launch
// stays 1568, avoiding R12's collapse); h(t0) bf16 + c(t0) fp32 staged in
// LDS ([px][ch], 16B-aligned b128 A-reads). Phase B: t0+1 on the 8x8
// interior. c is double-buffered globally (cross-block race). 8 launches.
__global__ __launch_bounds__(256, 4) void pair_step_mfma(
    const __hip_bfloat16* __restrict__ zx,   // [64][373248]
    const __hip_bfloat16* __restrict__ h_in, // h(t0-1) [8,54,54,16] bf16
    __hip_bfloat16* __restrict__ h_out,      // h(t0+1)
    const float* __restrict__ c_in,          // c(t0-1) [16][23328] planar
    float* __restrict__ c_out,               // c(t0+1)
    const __hip_bfloat16* __restrict__ wrb,  // [4][5][64][8] bf16
    const float* __restrict__ bias,          // [64]
    int t0)
{
    int region = blockIdx.x;                 // 0..48
    int tx = region % 7, ty = region / 7;
    int x0 = tx*8, y0 = ty*8;
    int b  = blockIdx.y;
    int wv = threadIdx.x >> 6;               // 0..3
    int lane = threadIdx.x & 63;
    int quad = lane >> 4;
    int ch = lane & 15;

    const __hip_bfloat16* hb = h_in + (size_t)b * SPIX * 16;
    const unsigned short* zxu = (const unsigned short*)zx;
    const s8v* wb = (const s8v*)wrb;
    size_t ptb = (size_t)b * (TT*SPIX);
    size_t cb0 = (size_t)b * SPIX;

    float b_i = bias[ch], b_f = bias[16+ch], b_g = bias[32+ch], b_o = bias[48+ch];

    __shared__ unsigned short htile[112*16]; // h(t0) bf16, p = py*10+px (10x10)
    __shared__ float          ctile[112*16]; // c(t0) fp32

    // ---- Phase A: t0 on ext region (-1..8)^2, 7 m-tiles of 16 px ----
    #pragma unroll 1
    for (int mt = wv; mt < 7; mt += 4) {
        int pm = mt*16 + (lane & 15);        // 0..111; valid < 100
        int py = pm / 10, px = pm % 10;
        int gy = y0 + py - 1, gx = x0 + px - 1;
        bool pvalid = pm < 100;

        f4v acc0 = {0.f,0.f,0.f,0.f}, acc1 = acc0, acc2 = acc0, acc3 = acc0;
        #pragma unroll
        for (int ks = 0; ks < 5; ++ks) {
            int blk = ks*4 + quad;
            s8v a = (s8v){0,0,0,0,0,0,0,0};
            if (blk < 18 && pvalid) {
                int tap = blk >> 1, half = blk & 1;
                int ky = tap / 3, kx = tap - ky*3;
                int hy = gy + ky - 1, hx = gx + kx - 1;
                if ((hy >= 0) & (hy < HO) & (hx >= 0) & (hx < WO))
                    a = *(const s8v*)(hb + ((size_t)hy*WO + hx)*16 + half*8);
            }
            acc0 = __builtin_amdgcn_mfma_f32_16x16x32_bf16(a, wb[(0*5+ks)*64 + lane], acc0, 0,0,0);
            acc1 = __builtin_amdgcn_mfma_f32_16x16x32_bf16(a, wb[(1*5+ks)*64 + lane], acc1, 0,0,0);
            acc2 = __builtin_amdgcn_mfma_f32_16x16x32_bf16(a, wb[(2*5+ks)*64 + lane], acc2, 0,0,0);
            acc3 = __builtin_amdgcn_mfma_f32_16x16x32_bf16(a, wb[(3*5+ks)*64 + lane], acc3, 0,0,0);
        }
        float* a0 = (float*)&acc0; float* a1 = (float*)&acc1;
        float* a2 = (float*)&acc2; float* a3 = (float*)&acc3;
        #pragma unroll
        for (int reg = 0; reg < 4; ++reg) {
            int p = mt*16 + quad*4 + reg;
            if (p < 100) {
                int py2 = p / 10, px2 = p % 10;
                int gy2 = y0 + py2 - 1, gx2 = x0 + px2 - 1;
                unsigned short hu = 0;
                float cc = 0.f;
                if ((gy2 >= 0) & (gy2 < HO) & (gx2 >= 0) & (gx2 < WO)) {
                    int r = gy2*WO + gx2;
                    size_t ptz = ptb + (size_t)t0 * SPIX + r;
                    float zi = bf2f(zxu[(size_t)( 0 + ch)*NPT + ptz]);
                    float zf = bf2f(zxu[(size_t)(16 + ch)*NPT + ptz]);
                    float zg = bf2f(zxu[(size_t)(32 + ch)*NPT + ptz]);
                    float zo = bf2f(zxu[(size_t)(48 + ch)*NPT + ptz]);
                    float cold = c_in[(size_t)ch*NPIX + cb0 + r];
                    float iv = hsig (a0[reg] + zi + b_i);
                    float fv = hsig (a1[reg] + zf + b_f);
                    float gv = tanhf(a2[reg] + zg + b_g);
                    float ov = hsig (a3[reg] + zo + b_o);
                    cc = fv * cold + iv * gv;
                    hu = f2bfu(ov * tanhf(cc));
                }
                htile[p*16 + ch] = hu;
                ctile[p*16 + ch] = cc;
            }
        }
    }
    __syncthreads();

    // ---- Phase B: t0+1 on the 8x8 interior, 1 m-tile per wave ----
    {
        int m = lane & 15;
        int pin = wv*16 + m;                 // 0..63
        int py = pin >> 3, px = pin & 7;

        f4v acc0 = {0.f,0.f,0.f,0.f}, acc1 = acc0, acc2 = acc0, acc3 = acc0;
        #pragma unroll
        for (int ks = 0; ks < 5; ++ks) {
            int blk = ks*4 + quad;
            s8v a = (s8v){0,0,0,0,0,0,0,0};
            if (blk < 18) {
                int tap = blk >> 1, half = blk & 1;
                int ky = tap / 3, kx = tap - ky*3;
                int idx = (py + ky)*10 + (px + kx);   // ext coords +1 folded in
                a = *(const s8v*)&htile[idx*16 + half*8];
            }
            acc0 = __builtin_amdgcn_mfma_f32_16x16x32_bf16(a, wb[(0*5+ks)*64 + lane], acc0, 0,0,0);
            acc1 = __builtin_amdgcn_mfma_f32_16x16x32_bf16(a, wb[(1*5+ks)*64 + lane], acc1, 0,0,0);
            acc2 = __builtin_amdgcn_mfma_f32_16x16x32_bf16(a, wb[(2*5+ks)*64 + lane], acc2, 0,0,0);
            acc3 = __builtin_amdgcn_mfma_f32_16x16x32_bf16(a, wb[(3*5+ks)*64 + lane], acc3, 0,0,0);
        }
        float* a0 = (float*)&acc0; float* a1 = (float*)&acc1;
        float* a2 = (float*)&acc2; float* a3 = (float*)&acc3;
        #pragma unroll
        for (int reg = 0; reg < 4; ++reg) {
            int p = wv*16 + quad*4 + reg;
            int py2 = p >> 3, px2 = p & 7;
            int gy = y0 + py2, gx = x0 + px2;
            if ((gy < HO) & (gx < WO)) {
                int r = gy*WO + gx;
                size_t ptz = ptb + (size_t)(t0+1) * SPIX + r;
                float zi = bf2f(zxu[(size_t)( 0 + ch)*NPT + ptz]);
                float zf = bf2f(zxu[(size_t)(16 + ch)*NPT + ptz]);
                float zg = bf2f(zxu[(size_t)(32 + ch)*NPT + ptz]);
                float zo = bf2f(zxu[(size_t)(48 + ch)*NPT + ptz]);
                float cold = ctile[((py2+1)*10 + (px2+1))*16 + ch];
                float iv = hsig (a0[reg] + zi + b_i);
                float fv = hsig (a1[reg] + zf + b_f);
                float gv = tanhf(a2[reg] + zg + b_g);
                float ov = hsig (a3[reg] + zo + b_o);
                float cc = fv * cold + iv * gv;
                c_out[(size_t)ch*NPIX + cb0 + r] = cc;
                ((unsigned short*)h_out)[((size_t)(cb0 + r))*16 + ch] = f2bfu(ov * tanhf(cc));
            }
        }
    }
}

// Kernel 3: spatial mean (bf16 h) -> dense(16->6) -> softmax. One block per b.
__global__ __launch_bounds__(256) void head_kernel(
    const __hip_bfloat16* __restrict__ h,   // [8,54,54,16] bf16
    const float* __restrict__ dw,   // [16,6]
    const float* __restrict__ db,   // [6]
    float* __restrict__ out)        // [8,6]
{
    int b = blockIdx.x;
    int tid = threadIdx.x;
    const __hip_bfloat16* hb = h + (size_t)b * SPIX * 16;
    float s = 0.0f;
    for (int i = tid; i < SPIX*16; i += 256) s += __bfloat162float(hb[i]);
    __shared__ float red[256];
    red[tid] = s;
    __syncthreads();
    for (int st = 128; st >= 16; st >>= 1) {
        if (tid < st) red[tid] += red[tid + st];
        __syncthreads();
    }
    __shared__ float logits[8];
    if (tid < NC) {
        float l = db[tid];
        #pragma unroll
        for (int ch = 0; ch < 16; ++ch)
            l += (red[ch] * (1.0f/2916.0f)) * dw[ch*NC + tid];
        logits[tid] = l;
    }
    __syncthreads();
    if (tid < NC) {
        float m = -1e30f;
        for (int k = 0; k < NC; ++k) m = fmaxf(m, logits[k]);
        float e = expf(logits[tid] - m);
        float d = 0.0f;
        for (int k = 0; k < NC; ++k) d += expf(logits[k] - m);
        out[b*NC + tid] = e / d;
    }
}

extern "C" void kernel_launch(void* const* d_in, const int* in_sizes, int n_in,
                              void* d_out, int out_size, void* d_ws, size_t ws_size,
                              hipStream_t stream) {
    const float* x      = (const float*)d_in[0];
    const float* conv_w = (const float*)d_in[1];
    const float* conv_b = (const float*)d_in[2];
    const float* wk     = (const float*)d_in[3];
    const float* wr     = (const float*)d_in[4];
    const float* bias   = (const float*)d_in[5];
    const float* dw     = (const float*)d_in[6];
    const float* db     = (const float*)d_in[7];
    float* out = (float*)d_out;

    char* base = (char*)d_ws;
    __hip_bfloat16* pooled = (__hip_bfloat16*)base;                 // 12.85 MB
    __hip_bfloat16* hA  = pooled + POOLED_BF16;                     // 746 KB
    __hip_bfloat16* hB  = hA + NPIX*16;
    __hip_bfloat16* wkb = hB + NPIX*16;                             // 20 KB
    __hip_bfloat16* wrb = wkb + 10240;                              // 20 KB
    __hip_bfloat16* cwb = wrb + 10240;                              // 6 KB
    float* cA = (float*)(cwb + 3072);                               // 1.49 MB
    float* cB = cA + NPIX*16;                                       // 1.49 MB
    __hip_bfloat16* zx  = (__hip_bfloat16*)(cB + NPIX*16);          // 47.8 MB
    // xpad parity copies ALIAS zx (consumed before zx is written).
    __hip_bfloat16* xp0 = zx;
    __hip_bfloat16* xp1 = zx + XPAD_ELEMS;

    // h(-1) = 0 (bf16 zero = 0x0000), c(-1) = 0
    hipMemsetAsync(hA, 0, (size_t)NPIX * 16 * sizeof(__hip_bfloat16), stream);
    hipMemsetAsync(cA, 0, (size_t)NPIX * 16 * sizeof(float), stream);

    w_prepack_kernel<<<dim3(40), dim3(256), 0, stream>>>(wk, wkb);
    w_prepack_kernel<<<dim3(40), dim3(256), 0, stream>>>(wr, wrb);
    cw_prepack_kernel<<<dim3(12), dim3(256), 0, stream>>>(conv_w, cwb);
    xpad_kernel<<<dim3(5310), dim3(256), 0, stream>>>(x, xp0, xp1);
    conv_mfma_kernel<<<dim3(25088), dim3(256), 0, stream>>>(xp0, xp1, cwb, conv_b, pooled);
    zx_mfma_kernel<<<dim3(5832), dim3(256), 0, stream>>>(pooled, wkb, zx);

    // 8 pair launches: j reads state (2j-1), writes state (2j+1).
    for (int j = 0; j < 8; ++j) {
        const __hip_bfloat16* hin  = (j & 1) ? hB : hA;
        __hip_bfloat16*       hout = (j & 1) ? hA : hB;
        const float* cin  = (j & 1) ? cB : cA;
        float*       cout = (j & 1) ? cA : cB;
        pair_step_mfma<<<dim3(49, 8), dim3(256), 0, stream>>>(
            zx, hin, hout, cin, cout, wrb, bias, 2*j);
    }
    // j=7 wrote hA
    head_kernel<<<dim3(8), dim3(256), 0, stream>>>(hA, dw, db, out);
}

// Round 19
// 317.104 us; speedup vs baseline: 1.7525x; 1.7525x over previous
//
#include <hip/hip_runtime.h>
#include <hip/hip_bf16.h>
#include <math.h>

// Problem dims
#define BB 8
#define TT 16
#define HH 112
#define WW 112
#define CC 3
#define FF 16
#define HP 56
#define WP 56
#define HO 54
#define WO 54
#define NC 6

#define NPIX (BB*HO*WO)               // 23328
#define SPIX (HO*WO)                  // 2916
#define NPT  (BB*TT*SPIX)             // 373248  (b,t,pixel)
#define POOLED_BF16  (128*56*56*16)   // 6,422,528 bf16

// xpad: per-frame bf16 rows with halo + pad: 118 rows x 360 elems
#define XROW 360
#define XFRM (118*XROW)               // 42,480
#define XPAD_ELEMS (128*XFRM)         // 5,437,440 per parity copy

typedef __attribute__((ext_vector_type(8))) short s8v;   // 8 bf16 (4 VGPRs)
typedef __attribute__((ext_vector_type(4))) float f4v;   // MFMA acc

__device__ __forceinline__ float hsig(float x) {
    return fminf(fmaxf(0.2f*x + 0.5f, 0.0f), 1.0f);
}
__device__ __forceinline__ unsigned pk2(float lo, float hi) {
    union { __hip_bfloat16 h; unsigned short u; } a, b;
    a.h = __float2bfloat16(lo); b.h = __float2bfloat16(hi);
    return ((unsigned)b.u << 16) | (unsigned)a.u;
}
__device__ __forceinline__ float bf2f(unsigned short u) {
    union { unsigned v; float f; } x; x.v = ((unsigned)u) << 16; return x.f;
}
__device__ __forceinline__ unsigned short f2bfu(float f) {
    union { __hip_bfloat16 h; unsigned short u; } v;
    v.h = __float2bfloat16(f); return v.u;
}

// Kernel 0a: prepack a [3,3,16,64] weight tensor into MFMA B-fragment order
// (K=144 pad 160): out[nt][ks][lane][j]. Used for BOTH wk and wr.
__global__ __launch_bounds__(256) void w_prepack_kernel(
    const float* __restrict__ w, __hip_bfloat16* __restrict__ wb)
{
    int i = blockIdx.x * 256 + threadIdx.x;        // 40*256 = 10240 exact
    int j    = i & 7;
    int lane = (i >> 3) & 63;
    int ks   = (i >> 9) % 5;
    int nt   = (i >> 9) / 5;
    int k = ks*32 + ((lane >> 4) & 3)*8 + j;
    int n = nt*16 + (lane & 15);
    float v = 0.f;
    if (k < 144) {
        int tap = k >> 4, ci = k & 15;
        v = w[tap*1024 + ci*64 + n];
    }
    wb[i] = __float2bfloat16(v);
}

// Kernel 0b: prepack conv weights [7,7,3,16] (K = 7 rows x 24, pad 192).
__global__ __launch_bounds__(256) void cw_prepack_kernel(
    const float* __restrict__ cw, __hip_bfloat16* __restrict__ cwb)
{
    int i = blockIdx.x * 256 + threadIdx.x;        // 12*256 = 3072 exact
    int j    = i & 7;
    int lane = (i >> 3) & 63;
    int ks   = i >> 9;                             // 0..5
    int k = ks*32 + ((lane >> 4) & 3)*8 + j;
    int n = lane & 15;
    float v = 0.f;
    if (k < 168) {
        int row = k / 24, idx = k % 24;
        if (idx < 21) {
            int kx = idx / 3, ci = idx % 3;
            v = cw[((row*7 + kx)*3 + ci)*16 + n];
        }
    }
    cwb[i] = __float2bfloat16(v);
}

// Kernel 0c: build bf16 padded x rows, TWO parity-shifted copies.
__global__ __launch_bounds__(256) void xpad_kernel(
    const float* __restrict__ x,
    __hip_bfloat16* __restrict__ xp0,
    __hip_bfloat16* __restrict__ xp1)
{
    int idx = blockIdx.x * 256 + threadIdx.x;      // 5310*256 = 1,359,360 exact
    int e4 = idx % 90;
    int rr = (idx / 90) % 118;
    int fr = idx / (90*118);
    int e0 = e4 * 4;
    int ir = rr - 3;
    const float* xf = x + (size_t)fr * (112*336);
    bool rowok = (ir >= 0) & (ir < 112);

    float v[5];
    #pragma unroll
    for (int i = 0; i < 5; ++i) {
        int s = e0 - 1 + i;
        bool ok = rowok & (s >= 9) & (s < 345);
        v[i] = ok ? xf[ir*336 + (s - 9)] : 0.f;
    }
    size_t o = ((size_t)fr*118 + rr) * XROW + e0;
    uint2 a0, a1;
    a0.x = pk2(v[1], v[2]); a0.y = pk2(v[3], v[4]);
    a1.x = pk2(v[0], v[1]); a1.y = pk2(v[2], v[3]);
    *(uint2*)&xp0[o] = a0;
    *(uint2*)&xp1[o] = a1;
}

// Kernel 1: conv 7x7 + bias + relu + maxpool via MFMA, 4 m-tiles per wave.
// One wave = 16 pooled px (4 m-tiles of 4 px x 4 pool pos); B-fragments
// loaded ONCE and reused x4 -> 24 MFMA/wave, wave count 100352 -> 25088.
// (R17: 6 MFMA/wave ran at MfmaUtil 6%, VALUBusy 34% - fixed per-wave cost
// and address math dominated.) Grid (49, 128): fr from blockIdx.y.
__global__ __launch_bounds__(256, 4) void conv_mfma_kernel(
    const __hip_bfloat16* __restrict__ xp0,
    const __hip_bfloat16* __restrict__ xp1,
    const __hip_bfloat16* __restrict__ cwb,  // [6][64][8]
    const float* __restrict__ cb,            // [16]
    __hip_bfloat16* __restrict__ pooled)     // [128,56,56,16] bf16
{
    int wv = threadIdx.x >> 6;
    int lane = threadIdx.x & 63;
    int quad = lane >> 4;
    int fr = blockIdx.y;
    int p0 = blockIdx.x * 64 + wv * 16;      // pooled px base, 16 per wave

    const s8v* wbp = (const s8v*)cwb;
    s8v bfrag[6];
    #pragma unroll
    for (int ks = 0; ks < 6; ++ks) bfrag[ks] = wbp[ks*64 + lane];

    const __hip_bfloat16* x0f = xp0 + (size_t)fr*XFRM;
    const __hip_bfloat16* x1f = xp1 + (size_t)fr*XFRM;

    f4v acc[4];
    #pragma unroll
    for (int j = 0; j < 4; ++j) {
        int m = lane & 15;
        int pp = p0 + j*4 + (m >> 2);
        int pos = m & 3;
        int pr = pp / 56, pc = pp % 56;
        int oh = 2*pr + (pos >> 1);
        int ow = 2*pc + (pos & 1);
        const __hip_bfloat16* xrow = ((ow & 1) ? x1f : x0f) + ow*3 + (ow & 1);

        f4v a4 = {0.f,0.f,0.f,0.f};
        #pragma unroll
        for (int ks = 0; ks < 6; ++ks) {
            int blk = ks*4 + quad;
            s8v a = (s8v){0,0,0,0,0,0,0,0};
            if (blk < 21) {
                int row = blk / 3;
                int off = (blk % 3) * 8;
                a = *(const s8v*)(xrow + (size_t)(oh + row)*XROW + off);
            }
            a4 = __builtin_amdgcn_mfma_f32_16x16x32_bf16(a, bfrag[ks], a4, 0,0,0);
        }
        acc[j] = a4;
    }

    // Epilogue: lane quad owns pooled px p0+j*4+quad, ch nlo; regs = 4 pos.
    int nlo = lane & 15;
    float bias_n = cb[nlo];
    #pragma unroll
    for (int j = 0; j < 4; ++j) {
        float* ap = (float*)&acc[j];
        float mx = fmaxf(fmaxf(ap[0], ap[1]), fmaxf(ap[2], ap[3]));
        float vv = fmaxf(mx + bias_n, 0.f);
        ((unsigned short*)pooled)[((size_t)fr*3136 + p0 + j*4 + quad)*16 + nlo] = f2bfu(vv);
    }
}

// Kernel 2a: zx via MFMA (R14, verified). One wave = 16 pt x 64 gates.
__global__ __launch_bounds__(256, 4) void zx_mfma_kernel(
    const __hip_bfloat16* __restrict__ pooled,  // [128][56][56][16] bf16
    const __hip_bfloat16* __restrict__ wkb,     // [4][5][64][8] bf16
    __hip_bfloat16* __restrict__ zx)            // [64][373248] bf16
{
    int wid  = (blockIdx.x << 2) + (threadIdx.x >> 6);  // 0..23327
    int lane = threadIdx.x & 63;
    int quad = lane >> 4;
    int pt0  = wid << 4;
    int m    = pt0 + (lane & 15);

    int b  = m / (TT*SPIX);
    int rt = m % (TT*SPIX);
    int tt = rt / SPIX;
    int r  = rt % SPIX;
    int oh = r / WO, ow = r % WO;
    const __hip_bfloat16* pf = pooled + (size_t)(b*TT + tt) * (HP*WP*16);

    f4v acc0 = {0.f,0.f,0.f,0.f}, acc1 = acc0, acc2 = acc0, acc3 = acc0;
    const s8v* wb = (const s8v*)wkb;

    #pragma unroll
    for (int ks = 0; ks < 5; ++ks) {
        int blk = ks*4 + quad;
        s8v a;
        if (blk < 18) {
            int tap = blk >> 1, half = blk & 1;
            int ky = tap / 3, kx = tap - ky*3;
            a = *(const s8v*)(pf + ((size_t)(oh+ky)*WP + (ow+kx))*16 + half*8);
        } else {
            a = (s8v){0,0,0,0,0,0,0,0};
        }
        acc0 = __builtin_amdgcn_mfma_f32_16x16x32_bf16(a, wb[(0*5+ks)*64 + lane], acc0, 0,0,0);
        acc1 = __builtin_amdgcn_mfma_f32_16x16x32_bf16(a, wb[(1*5+ks)*64 + lane], acc1, 0,0,0);
        acc2 = __builtin_amdgcn_mfma_f32_16x16x32_bf16(a, wb[(2*5+ks)*64 + lane], acc2, 0,0,0);
        acc3 = __builtin_amdgcn_mfma_f32_16x16x32_bf16(a, wb[(3*5+ks)*64 + lane], acc3, 0,0,0);
    }

    int nlo = lane & 15;
    size_t prow = (size_t)pt0 + quad*4;
    f4v accs[4] = {acc0, acc1, acc2, acc3};
    #pragma unroll
    for (int nt = 0; nt < 4; ++nt) {
        int n = nt*16 + nlo;
        uint2 u;
        u.x = pk2(accs[nt].x, accs[nt].y);
        u.y = pk2(accs[nt].z, accs[nt].w);
        *(uint2*)&zx[(size_t)n * NPT + prow] = u;
    }
}

// Kernel 2b: one ConvLSTM step via MFMA (R15/R16, verified). 16 launches —
// R12/R17 both showed 2-step fusion regresses (per-wave work trebles,
// zx loads scalarize); ~13 us/launch is the scan floor for this shape.
__global__ __launch_bounds__(256, 4) void lstm_step_mfma(
    const __hip_bfloat16* __restrict__ zx,   // [64][373248]
    const __hip_bfloat16* __restrict__ h_in, // [8,54,54,16] bf16
    __hip_bfloat16* __restrict__ h_out,
    float* __restrict__ cpl,                 // [16][23328] planar fp32
    const __hip_bfloat16* __restrict__ wrb,  // [4][5][64][8] bf16
    const float* __restrict__ bias,          // [64]
    int t)
{
    int wid = (blockIdx.x << 2) + (threadIdx.x >> 6);
    if (wid >= 1458) return;                 // no barriers below
    int lane = threadIdx.x & 63;
    int quad = lane >> 4;
    int pt0  = wid << 4;
    int m    = pt0 + (lane & 15);

    int b  = m / SPIX;
    int r  = m % SPIX;
    int oh = r / WO, ow = r % WO;
    const __hip_bfloat16* hb = h_in + (size_t)b * SPIX * 16;

    f4v acc0 = {0.f,0.f,0.f,0.f}, acc1 = acc0, acc2 = acc0, acc3 = acc0;
    const s8v* wb = (const s8v*)wrb;

    #pragma unroll
    for (int ks = 0; ks < 5; ++ks) {
        int blk = ks*4 + quad;
        s8v a = (s8v){0,0,0,0,0,0,0,0};
        if (blk < 18) {
            int tap = blk >> 1, half = blk & 1;
            int ky = tap / 3, kx = tap - ky*3;
            int hy = oh + ky - 1, hx = ow + kx - 1;   // SAME pad
            if ((hy >= 0) & (hy < HO) & (hx >= 0) & (hx < WO))
                a = *(const s8v*)(hb + ((size_t)hy*WO + hx)*16 + half*8);
        }
        acc0 = __builtin_amdgcn_mfma_f32_16x16x32_bf16(a, wb[(0*5+ks)*64 + lane], acc0, 0,0,0);
        acc1 = __builtin_amdgcn_mfma_f32_16x16x32_bf16(a, wb[(1*5+ks)*64 + lane], acc1, 0,0,0);
        acc2 = __builtin_amdgcn_mfma_f32_16x16x32_bf16(a, wb[(2*5+ks)*64 + lane], acc2, 0,0,0);
        acc3 = __builtin_amdgcn_mfma_f32_16x16x32_bf16(a, wb[(3*5+ks)*64 + lane], acc3, 0,0,0);
    }

    // Epilogue: lane owns channel ch for pixels pm..pm+3 (one b: 2916%4==0).
    int ch = lane & 15;
    int pm = pt0 + quad*4;
    int b2 = pm / SPIX, r2 = pm % SPIX;
    size_t ptz = (size_t)b2 * (TT*SPIX) + (size_t)t * SPIX + r2;

    ushort4 zi = *(const ushort4*)&zx[(size_t)( 0 + ch) * NPT + ptz];
    ushort4 zf = *(const ushort4*)&zx[(size_t)(16 + ch) * NPT + ptz];
    ushort4 zg = *(const ushort4*)&zx[(size_t)(32 + ch) * NPT + ptz];
    ushort4 zo = *(const ushort4*)&zx[(size_t)(48 + ch) * NPT + ptz];

    float4 cold = *(float4*)&cpl[(size_t)ch * NPIX + pm];
    float b_i = bias[ch], b_f = bias[16+ch], b_g = bias[32+ch], b_o = bias[48+ch];

    float4 cnew;
    unsigned short hn[4];
    float* co = &cold.x; float* cn = &cnew.x;
    const unsigned short* zip = (const unsigned short*)&zi;
    const unsigned short* zfp = (const unsigned short*)&zf;
    const unsigned short* zgp = (const unsigned short*)&zg;
    const unsigned short* zop = (const unsigned short*)&zo;
    float* a0 = (float*)&acc0; float* a1 = (float*)&acc1;
    float* a2 = (float*)&acc2; float* a3 = (float*)&acc3;
    #pragma unroll
    for (int reg = 0; reg < 4; ++reg) {
        float iv = hsig (a0[reg] + bf2f(zip[reg]) + b_i);
        float fv = hsig (a1[reg] + bf2f(zfp[reg]) + b_f);
        float gv = tanhf(a2[reg] + bf2f(zgp[reg]) + b_g);
        float ov = hsig (a3[reg] + bf2f(zop[reg]) + b_o);
        float cc = fv * co[reg] + iv * gv;
        cn[reg] = cc;
        hn[reg] = f2bfu(ov * tanhf(cc));
    }
    *(float4*)&cpl[(size_t)ch * NPIX + pm] = cnew;
    #pragma unroll
    for (int reg = 0; reg < 4; ++reg)
        ((unsigned short*)h_out)[(size_t)(pm + reg) * 16 + ch] = hn[reg];
}

// Kernel 3: spatial mean (bf16 h) -> dense(16->6) -> softmax. One block per b.
__global__ __launch_bounds__(256) void head_kernel(
    const __hip_bfloat16* __restrict__ h,   // [8,54,54,16] bf16
    const float* __restrict__ dw,   // [16,6]
    const float* __restrict__ db,   // [6]
    float* __restrict__ out)        // [8,6]
{
    int b = blockIdx.x;
    int tid = threadIdx.x;
    const __hip_bfloat16* hb = h + (size_t)b * SPIX * 16;
    float s = 0.0f;
    for (int i = tid; i < SPIX*16; i += 256) s += __bfloat162float(hb[i]);
    __shared__ float red[256];
    red[tid] = s;
    __syncthreads();
    for (int st = 128; st >= 16; st >>= 1) {
        if (tid < st) red[tid] += red[tid + st];
        __syncthreads();
    }
    __shared__ float logits[8];
    if (tid < NC) {
        float l = db[tid];
        #pragma unroll
        for (int ch = 0; ch < 16; ++ch)
            l += (red[ch] * (1.0f/2916.0f)) * dw[ch*NC + tid];
        logits[tid] = l;
    }
    __syncthreads();
    if (tid < NC) {
        float m = -1e30f;
        for (int k = 0; k < NC; ++k) m = fmaxf(m, logits[k]);
        float e = expf(logits[tid] - m);
        float d = 0.0f;
        for (int k = 0; k < NC; ++k) d += expf(logits[k] - m);
        out[b*NC + tid] = e / d;
    }
}

extern "C" void kernel_launch(void* const* d_in, const int* in_sizes, int n_in,
                              void* d_out, int out_size, void* d_ws, size_t ws_size,
                              hipStream_t stream) {
    const float* x      = (const float*)d_in[0];
    const float* conv_w = (const float*)d_in[1];
    const float* conv_b = (const float*)d_in[2];
    const float* wk     = (const float*)d_in[3];
    const float* wr     = (const float*)d_in[4];
    const float* bias   = (const float*)d_in[5];
    const float* dw     = (const float*)d_in[6];
    const float* db     = (const float*)d_in[7];
    float* out = (float*)d_out;

    char* base = (char*)d_ws;
    __hip_bfloat16* pooled = (__hip_bfloat16*)base;                 // 12.85 MB
    __hip_bfloat16* hA  = pooled + POOLED_BF16;                     // 746 KB
    __hip_bfloat16* hB  = hA + NPIX*16;
    __hip_bfloat16* wkb = hB + NPIX*16;                             // 20 KB
    __hip_bfloat16* wrb = wkb + 10240;                              // 20 KB
    __hip_bfloat16* cwb = wrb + 10240;                              // 6 KB
    float* cpl = (float*)(cwb + 3072);                              // 1.49 MB
    __hip_bfloat16* zx  = (__hip_bfloat16*)(cpl + NPIX*16);         // 47.8 MB
    // xpad parity copies ALIAS zx (consumed before zx is written).
    __hip_bfloat16* xp0 = zx;
    __hip_bfloat16* xp1 = zx + XPAD_ELEMS;

    // h0 = 0 (bf16 zero = 0x0000), c0 = 0
    hipMemsetAsync(hA,  0, (size_t)NPIX * 16 * sizeof(__hip_bfloat16), stream);
    hipMemsetAsync(cpl, 0, (size_t)NPIX * 16 * sizeof(float), stream);

    w_prepack_kernel<<<dim3(40), dim3(256), 0, stream>>>(wk, wkb);
    w_prepack_kernel<<<dim3(40), dim3(256), 0, stream>>>(wr, wrb);
    cw_prepack_kernel<<<dim3(12), dim3(256), 0, stream>>>(conv_w, cwb);
    xpad_kernel<<<dim3(5310), dim3(256), 0, stream>>>(x, xp0, xp1);
    conv_mfma_kernel<<<dim3(49, 128), dim3(256), 0, stream>>>(xp0, xp1, cwb, conv_b, pooled);
    zx_mfma_kernel<<<dim3(5832), dim3(256), 0, stream>>>(pooled, wkb, zx);

    for (int t = 0; t < TT; ++t) {
        const __hip_bfloat16* hin  = (t & 1) ? hB : hA;
        __hip_bfloat16*       hout = (t & 1) ? hA : hB;
        lstm_step_mfma<<<dim3(365), dim3(256), 0, stream>>>(
            zx, hin, hout, cpl, wrb, bias, t);
    }
    // t=15 (odd) wrote hA
    head_kernel<<<dim3(8), dim3(256), 0, stream>>>(hA, dw, db, out);
}